// Round 1
// baseline (250.120 us; speedup 1.0000x reference)
//
#include <hip/hip_runtime.h>
#include <float.h>

#define N_NODES 4096
#define IN_FEAT 256
#define N_HEADS 8
#define N_HIDDEN 64
#define OUT_FEAT (N_HEADS * N_HIDDEN)  // 512
#define MAXE 1024
#define NEG_SLOPE 0.2f

// ---------------- GEMM: G[i][o] = sum_k H[i][k] * W[o][k] ----------------
// 64x64 tile, BK=64, 256 threads, 4x4 per thread. K-major LDS ([k][m], pad 68
// keeps float4 reads 16B-aligned and inner reads conflict-free).
__global__ __launch_bounds__(256) void gemm_hw(const float* __restrict__ H,
                                               const float* __restrict__ W,
                                               float* __restrict__ G) {
  __shared__ float As[64][68];
  __shared__ float Bs[64][68];
  const int t = threadIdx.x;
  const int tx = t & 15, ty = t >> 4;
  const int bi = blockIdx.x, bo = blockIdx.y;
  float acc[4][4];
#pragma unroll
  for (int a = 0; a < 4; a++)
#pragma unroll
    for (int b = 0; b < 4; b++) acc[a][b] = 0.f;

  for (int kt = 0; kt < IN_FEAT; kt += 64) {
#pragma unroll
    for (int q = 0; q < 4; ++q) {
      int idx = q * 256 + t;
      int row = idx >> 4;        // 0..63
      int k4  = (idx & 15) << 2; // 0..60
      float4 av = *(const float4*)(H + (size_t)(bi * 64 + row) * IN_FEAT + kt + k4);
      As[k4 + 0][row] = av.x; As[k4 + 1][row] = av.y;
      As[k4 + 2][row] = av.z; As[k4 + 3][row] = av.w;
      float4 bv = *(const float4*)(W + (size_t)(bo * 64 + row) * IN_FEAT + kt + k4);
      Bs[k4 + 0][row] = bv.x; Bs[k4 + 1][row] = bv.y;
      Bs[k4 + 2][row] = bv.z; Bs[k4 + 3][row] = bv.w;
    }
    __syncthreads();
#pragma unroll
    for (int k = 0; k < 64; ++k) {
      float4 a = *(const float4*)&As[k][ty << 2];
      float4 b = *(const float4*)&Bs[k][tx << 2];
      float am[4] = {a.x, a.y, a.z, a.w};
      float bn[4] = {b.x, b.y, b.z, b.w};
#pragma unroll
      for (int mm = 0; mm < 4; mm++)
#pragma unroll
        for (int nn = 0; nn < 4; nn++)
          acc[mm][nn] = fmaf(am[mm], bn[nn], acc[mm][nn]);
    }
    __syncthreads();
  }
#pragma unroll
  for (int mm = 0; mm < 4; mm++) {
    float4 o = make_float4(acc[mm][0], acc[mm][1], acc[mm][2], acc[mm][3]);
    *(float4*)(G + (size_t)(bi * 64 + (ty << 2) + mm) * OUT_FEAT + bo * 64 + (tx << 2)) = o;
  }
}

// ---------------- el/er: dot(g[i,h,:], a_l/a_r) ----------------
// 8 threads per (i,h) pair; 32 pairs per 256-thread block.
__global__ __launch_bounds__(256) void elr_kernel(const float* __restrict__ G,
                                                  const float* __restrict__ a,
                                                  float* __restrict__ el,
                                                  float* __restrict__ er) {
  const int t = threadIdx.x;
  const int gid = blockIdx.x * 32 + (t >> 3);  // (i*8+h), 0..32767
  const int lane = t & 7;
  const float* grow = G + (size_t)gid * 64 + lane * 8;
  float4 v0 = *(const float4*)(grow);
  float4 v1 = *(const float4*)(grow + 4);
  const float* al = a + lane * 8;
  const float* ar = a + 64 + lane * 8;
  float4 l0 = *(const float4*)(al);
  float4 l1 = *(const float4*)(al + 4);
  float4 r0 = *(const float4*)(ar);
  float4 r1 = *(const float4*)(ar + 4);
  float sl = v0.x * l0.x + v0.y * l0.y + v0.z * l0.z + v0.w * l0.w +
             v1.x * l1.x + v1.y * l1.y + v1.z * l1.z + v1.w * l1.w;
  float sr = v0.x * r0.x + v0.y * r0.y + v0.z * r0.z + v0.w * r0.w +
             v1.x * r1.x + v1.y * r1.y + v1.z * r1.z + v1.w * r1.w;
#pragma unroll
  for (int off = 4; off; off >>= 1) {
    sl += __shfl_xor(sl, off);
    sr += __shfl_xor(sr, off);
  }
  if (lane == 0) { el[gid] = sl; er[gid] = sr; }
}

// ---------------- Gsum[c] = sum_i G[i][c] ----------------
__global__ __launch_bounds__(256) void gsum_kernel(const float* __restrict__ G,
                                                   float* __restrict__ gsum) {
  const int c = blockIdx.x * 256 + threadIdx.x;  // 0..511
  const int i0 = blockIdx.y * 256;
  float s = 0.f;
  for (int i = i0; i < i0 + 256; ++i) s += G[(size_t)i * OUT_FEAT + c];
  atomicAdd(&gsum[c], s);
}

// ---------------- main attention kernel: one block per row i ----------------
__global__ __launch_bounds__(256) void attn_kernel(
    const float* __restrict__ adj, const float* __restrict__ G,
    const float* __restrict__ el, const float* __restrict__ er,
    const float* __restrict__ gsum, float* __restrict__ out) {
  __shared__ int jlist[MAXE];
  __shared__ float ee[MAXE * N_HEADS];  // [jj][h], 32 KB
  __shared__ float el_s[N_HEADS], mh[N_HEADS], zh[N_HEADS];
  __shared__ int cnt;
  const int i = blockIdx.x;
  const int t = threadIdx.x;
  if (t == 0) cnt = 0;
  if (t < N_HEADS) el_s[t] = el[i * N_HEADS + t];
  __syncthreads();

  // Phase 1: scan adjacency row, compact edge list (order irrelevant).
  const float* row = adj + (size_t)i * N_NODES;
#pragma unroll
  for (int q = 0; q < 4; ++q) {
    int j0 = (q * 256 + t) * 4;
    float4 v = *(const float4*)(row + j0);
    if (v.x != 0.f) { int p = atomicAdd(&cnt, 1); if (p < MAXE) jlist[p] = j0; }
    if (v.y != 0.f) { int p = atomicAdd(&cnt, 1); if (p < MAXE) jlist[p] = j0 + 1; }
    if (v.z != 0.f) { int p = atomicAdd(&cnt, 1); if (p < MAXE) jlist[p] = j0 + 2; }
    if (v.w != 0.f) { int p = atomicAdd(&cnt, 1); if (p < MAXE) jlist[p] = j0 + 3; }
  }
  __syncthreads();
  const int deg = min(cnt, MAXE);

  // Phase 2: e = leaky_relu(el[i,h] + er[j,h]) for every (edge, head).
  for (int idx = t; idx < deg * N_HEADS; idx += 256) {
    int jj = idx >> 3, h = idx & 7;
    int j = jlist[jj];
    float x = el_s[h] + er[j * N_HEADS + h];
    ee[idx] = x > 0.f ? x : NEG_SLOPE * x;
  }
  __syncthreads();

  const int h = t >> 5, lane = t & 31;
  // Phase 3a: per-head max over edges; non-edges contribute 0 (deg < N).
  float m = -FLT_MAX;
  for (int jj = lane; jj < deg; jj += 32) m = fmaxf(m, ee[jj * 8 + h]);
#pragma unroll
  for (int off = 16; off; off >>= 1) m = fmaxf(m, __shfl_xor(m, off));
  if (deg < N_NODES) m = fmaxf(m, 0.f);
  if (lane == 0) mh[h] = m;
  __syncthreads();
  m = mh[h];

  // Phase 3b: w = exp(e - m) stored in place; Z includes (N-deg)*exp(-m).
  float z = 0.f;
  for (int jj = lane; jj < deg; jj += 32) {
    float w = __expf(ee[jj * 8 + h] - m);
    ee[jj * 8 + h] = w;
    z += w;
  }
#pragma unroll
  for (int off = 16; off; off >>= 1) z += __shfl_xor(z, off);
  const float em = __expf(-m);
  if (lane == 0) zh[h] = z + (float)(N_NODES - deg) * em;
  __syncthreads();

  // Phase 4: out[i,h,:] = ( sum_edges (w-em)*g[j,h,:] + em*Gsum[h,:] ) / Z
  const int f = lane * 2;
  float acc0 = 0.f, acc1 = 0.f;
#pragma unroll 4
  for (int jj = 0; jj < deg; ++jj) {
    float c = ee[jj * 8 + h] - em;
    int j = jlist[jj];
    float2 gv = *(const float2*)(G + (size_t)j * OUT_FEAT + h * 64 + f);
    acc0 = fmaf(c, gv.x, acc0);
    acc1 = fmaf(c, gv.y, acc1);
  }
  float2 gs = *(const float2*)(gsum + h * 64 + f);
  float invz = 1.f / zh[h];
  float* op = out + (size_t)i * OUT_FEAT + h * 64 + f;
  op[0] = (acc0 + em * gs.x) * invz;
  op[1] = (acc1 + em * gs.y) * invz;
}

extern "C" void kernel_launch(void* const* d_in, const int* in_sizes, int n_in,
                              void* d_out, int out_size, void* d_ws, size_t ws_size,
                              hipStream_t stream) {
  const float* h   = (const float*)d_in[0];
  const float* adj = (const float*)d_in[1];
  const float* W   = (const float*)d_in[2];
  const float* a   = (const float*)d_in[3];
  float* out = (float*)d_out;

  char* ws = (char*)d_ws;
  float* G    = (float*)ws;                       // 4096*512*4 = 8 MB
  float* el   = (float*)(ws + 8u * 1024 * 1024);  // 128 KB
  float* er   = el + N_NODES * N_HEADS;           // 128 KB
  float* gsum = er + N_NODES * N_HEADS;           // 2 KB

  hipMemsetAsync(gsum, 0, OUT_FEAT * sizeof(float), stream);
  gemm_hw<<<dim3(64, 8), 256, 0, stream>>>(h, W, G);
  elr_kernel<<<dim3(1024), 256, 0, stream>>>(G, a, el, er);
  gsum_kernel<<<dim3(2, 16), 256, 0, stream>>>(G, gsum);
  attn_kernel<<<dim3(N_NODES), 256, 0, stream>>>(adj, G, el, er, gsum, out);
}